// Round 6
// baseline (656.111 us; speedup 1.0000x reference)
//
#include <hip/hip_runtime.h>

#define DTC 0.02f
#define INV_DT_SKIP 2.5f            // 1/(0.02*20)
#define NBLK 64
#define NSTEP 50
#define NACT 500                    // active waves = 32-group chunks

typedef __attribute__((ext_vector_type(8))) __bf16 bf16x8;
typedef __attribute__((ext_vector_type(4))) float f32x4;
typedef __attribute__((ext_vector_type(8))) unsigned short us8;
typedef unsigned long long u64t;

__device__ inline unsigned short f2bf(float x) {        // RNE fp32->bf16
    unsigned u = __float_as_uint(x);
    unsigned r = u + 0x7FFF + ((u >> 16) & 1u);
    return (unsigned short)(r >> 16);
}
__device__ inline float bf2f(unsigned short h) {
    return __uint_as_float(((unsigned)h) << 16);
}
__device__ inline unsigned pack2(float a, float b) {
    return (unsigned)f2bf(a) | ((unsigned)f2bf(b) << 16);
}
// Agent-scoped (cross-XCD coherent) accesses for all cross-block data.
__device__ inline void gstore32(unsigned* p, unsigned v) {
    __hip_atomic_store(p, v, __ATOMIC_RELAXED, __HIP_MEMORY_SCOPE_AGENT);
}
__device__ inline unsigned gload32(const unsigned* p) {
    return __hip_atomic_load(p, __ATOMIC_RELAXED, __HIP_MEMORY_SCOPE_AGENT);
}
__device__ inline u64t gload64(const u64t* p) {
    return __hip_atomic_load(p, __ATOMIC_RELAXED, __HIP_MEMORY_SCOPE_AGENT);
}

// ---------------------------------------------------------------------------
// Neumann inverses (verified rounds 1-5). inv1 = (I-dt*Ap)^-1,
// inv2 = (3I-2dt*Ap)^-1.
// ---------------------------------------------------------------------------
__global__ __launch_bounds__(256) void kinv(const float* __restrict__ Ap,
                                            float* __restrict__ inv1,
                                            float* __restrict__ inv2) {
    const int t = threadIdx.x;
    const float coef  = (blockIdx.x == 0) ? DTC : (2.0f * DTC / 3.0f);
    const float scale = (blockIdx.x == 0) ? 1.0f : (1.0f / 3.0f);
    float* outp = (blockIdx.x == 0) ? inv1 : inv2;

    __shared__ float ET[64 * 68];
    __shared__ float XA[64 * 68];
    __shared__ float XB[64 * 68];

    for (int idx = t; idx < 4096; idx += 256) {
        int r = idx >> 6, c = idx & 63;
        float e = coef * Ap[idx];
        ET[c * 68 + r] = e;
        XA[r * 68 + c] = ((r == c) ? 1.0f : 0.0f) + e;
    }
    __syncthreads();

    const int rr = (t >> 4) << 2;
    const int cc = (t & 15) << 2;
    float* bufs[2] = {XA, XB};
    for (int it = 0; it < 3; it++) {
        const float* Xin = bufs[it & 1];
        float* Xout = bufs[(it + 1) & 1];
        float acc[4][4];
        #pragma unroll
        for (int i = 0; i < 4; i++)
            #pragma unroll
            for (int j = 0; j < 4; j++)
                acc[i][j] = ((rr + i) == (cc + j)) ? 1.0f : 0.0f;
        for (int k = 0; k < 64; k++) {
            float4 e4 = *(const float4*)&ET[k * 68 + rr];
            float4 x4 = *(const float4*)&Xin[k * 68 + cc];
            float ev[4] = {e4.x, e4.y, e4.z, e4.w};
            float xv[4] = {x4.x, x4.y, x4.z, x4.w};
            #pragma unroll
            for (int i = 0; i < 4; i++)
                #pragma unroll
                for (int j = 0; j < 4; j++)
                    acc[i][j] += ev[i] * xv[j];
        }
        __syncthreads();
        #pragma unroll
        for (int i = 0; i < 4; i++)
            #pragma unroll
            for (int j = 0; j < 4; j++)
                Xout[(rr + i) * 68 + cc + j] = acc[i][j];
        __syncthreads();
    }
    const float* Xf = bufs[1];
    for (int idx = t; idx < 4096; idx += 256) {
        int r = idx >> 6, c = idx & 63;
        outp[idx] = scale * Xf[r * 68 + c];
    }
}

__global__ void kzero(unsigned* __restrict__ flags) {
    if (threadIdx.x < NBLK) flags[threadIdx.x] = 0u;
}

// ---------------------------------------------------------------------------
// Parallel-flag grid barrier (monotone, no reset). Arrival = one agent store
// (no RMW serialization); detection = wave-0 64-lane coalesced flag load +
// __all. __syncthreads drains each wave's outstanding stores (vmcnt(0)
// before s_barrier) so the leader's flag publishes after the whole block's
// partial stores completed. 64 resident blocks (LDS 102KB -> 1 block/CU).
// ---------------------------------------------------------------------------
__device__ inline void flagbar(unsigned* flags, int blk, unsigned target) {
    __syncthreads();
    if (threadIdx.x < 64) {
        if (threadIdx.x == 0)
            __hip_atomic_store(&flags[blk], target, __ATOMIC_RELEASE, __HIP_MEMORY_SCOPE_AGENT);
        for (;;) {
            unsigned v = __hip_atomic_load(&flags[threadIdx.x], __ATOMIC_ACQUIRE,
                                           __HIP_MEMORY_SCOPE_AGENT);
            if (__all(v >= target)) break;
            __builtin_amdgcn_s_sleep(2);
        }
    }
    __syncthreads();
}

// ---------------------------------------------------------------------------
// Persistent kernel, 64 blocks, ONE barrier per step.
//   Phase A (verified r2-r5): z = a@W^T hi/lo bf16 MFMA from register-
//   resident W frags, f = u*dx+v*dy, LDS C->A relayout, proj MFMA vs
//   register P frags, block LDS reduce -> bf16-packed partial slot
//   (parity-double-buffered). flagbar.
//   Redundant reduce: every block sums all 64 slots itself (coalesced u64
//   agent loads, 8-deep MLP) -> f in registers (4 elems/thread; f_prev also
//   register-resident). BDF2 r -> LDS, solve a_next = cb*r + r@S^T hi/lo
//   MFMA (waves 0-1; verified r4-r5). Block 0 writes output at last step.
// WAR safety of pbuf double buffer: all blocks passed barrier k ==> all
// finished step k-1's reduce (program order), which last read parity(k+1).
// ---------------------------------------------------------------------------
__global__ __launch_bounds__(512, 2)
void kmain(const float* __restrict__ state,
           const float* __restrict__ Wu,
           const float* __restrict__ Wv,
           const float* __restrict__ Pp,
           const float* __restrict__ inv1,
           const float* __restrict__ inv2,
           unsigned* __restrict__ pbuf,     // 2 parities x 64 slots x 1024 u32
           unsigned* __restrict__ flags,    // NBLK flag words
           float* __restrict__ out) {
    const int t = threadIdx.x;
    const int l = t & 63;
    const int w = t >> 6;                 // wave 0..7
    const int blk = blockIdx.x;
    const int q = blk * 8 + w;            // global wave = 32-group chunk
    const bool active = (q < NACT);

    __shared__ float Ab[3][2176];         // a triple buffer, 32 rows x 68
    __shared__ float fb[8][2][16][36];    // per-wave f tile [mt][16b][K=32+pad]
    __shared__ float red[8][1024];        // per-wave proj partials (16b x 64p)
    __shared__ float rbuf[32 * 68];       // r, padded stride 68

    for (int i = t; i < 2048; i += 512) Ab[0][(i >> 6) * 68 + (i & 63)] = state[i];
    for (int i = t; i < 8192; i += 512) ((float*)red)[i] = 0.f;   // inactive waves stay 0

    const int nr = l & 15;
    const int c0 = (l >> 4) << 3;
    const float* W = (q < 250) ? Wu : Wv;
    const int gl0 = ((q < 250) ? q : q - 250) * 32;   // net-local group base

    // ---- register-resident fragments (verified r5) ----
    bf16x8 wf[2][4][2], pf[4], sf[4][2];
    if (active) {
        #pragma unroll
        for (int th = 0; th < 2; th++)
            #pragma unroll
            for (int rb = 0; rb < 4; rb++)
                #pragma unroll
                for (int kt = 0; kt < 2; kt++) {
                    const float* s = W + (size_t)(rb * 8000 + gl0 + th * 16 + nr) * 64 + kt * 32 + c0;
                    us8 o;
                    #pragma unroll
                    for (int j = 0; j < 8; j++) o[j] = f2bf(s[j]);
                    wf[th][rb][kt] = __builtin_bit_cast(bf16x8, o);
                }
        #pragma unroll
        for (int pt = 0; pt < 4; pt++) {
            const float* s = Pp + (size_t)(pt * 16 + nr) * 16000 + q * 32 + c0;
            us8 o;
            #pragma unroll
            for (int j = 0; j < 8; j++) o[j] = f2bf(s[j]);
            pf[pt] = __builtin_bit_cast(bf16x8, o);
        }
    }
    if (w < 2) {                            // S = inv2 - I/3 (B-frag layout)
        #pragma unroll
        for (int pt = 0; pt < 4; pt++)
            #pragma unroll
            for (int kt = 0; kt < 2; kt++) {
                int p = pt * 16 + nr;
                const float* s = inv2 + (size_t)p * 64 + kt * 32 + c0;
                us8 o;
                #pragma unroll
                for (int j = 0; j < 8; j++) {
                    float v = s[j] - ((p == kt * 32 + c0 + j) ? (1.0f / 3.0f) : 0.0f);
                    o[j] = f2bf(v);
                }
                sf[pt][kt] = __builtin_bit_cast(bf16x8, o);
            }
    }
    __syncthreads();

    int ia_prev = 2, ia_cur = 0, ia_next = 1;
    float fprev[4];                       // f_prev for elems 4t..4t+3

    for (int k = 0; k < NSTEP; k++) {
        const int par = k & 1;
        unsigned* pslot = pbuf + (size_t)par * (NBLK * 1024) + blk * 1024;

        // ================= phase A: rhs partials =================
        if (active) {
            bf16x8 ahi[2][2], alo[2][2];
            const float* ac = Ab[ia_cur];
            #pragma unroll
            for (int mt = 0; mt < 2; mt++)
                #pragma unroll
                for (int kt = 0; kt < 2; kt++) {
                    us8 hv, lv;
                    #pragma unroll
                    for (int j = 0; j < 8; j++) {
                        float x = ac[(mt * 16 + nr) * 68 + kt * 32 + c0 + j];
                        unsigned short h = f2bf(x);
                        hv[j] = h;
                        lv[j] = f2bf(x - bf2f(h));
                    }
                    ahi[mt][kt] = __builtin_bit_cast(bf16x8, hv);
                    alo[mt][kt] = __builtin_bit_cast(bf16x8, lv);
                }
            const int col = l & 15, q4 = l >> 4;
            #pragma unroll
            for (int mt = 0; mt < 2; mt++)
                #pragma unroll
                for (int th = 0; th < 2; th++) {
                    f32x4 z[4];
                    #pragma unroll
                    for (int rb = 0; rb < 4; rb++) {
                        f32x4 acc = {0.f, 0.f, 0.f, 0.f};
                        #pragma unroll
                        for (int kt = 0; kt < 2; kt++) {
                            acc = __builtin_amdgcn_mfma_f32_16x16x32_bf16(ahi[mt][kt], wf[th][rb][kt], acc, 0, 0, 0);
                            acc = __builtin_amdgcn_mfma_f32_16x16x32_bf16(alo[mt][kt], wf[th][rb][kt], acc, 0, 0, 0);
                        }
                        z[rb] = acc;
                    }
                    #pragma unroll
                    for (int r = 0; r < 4; r++) {
                        float f = z[0][r] * z[2][r] + z[1][r] * z[3][r];
                        fb[w][mt][q4 * 4 + r][th * 16 + col] = f;
                    }
                }
        }
        __syncthreads();

        bf16x8 ff[2];
        if (active) {
            #pragma unroll
            for (int mt = 0; mt < 2; mt++) {
                us8 fv;
                #pragma unroll
                for (int j = 0; j < 8; j++) fv[j] = f2bf(fb[w][mt][nr][c0 + j]);
                ff[mt] = __builtin_bit_cast(bf16x8, fv);
            }
        }

        #pragma unroll
        for (int mt = 0; mt < 2; mt++) {
            if (active) {
                const int col = l & 15, q4 = l >> 4;
                #pragma unroll
                for (int pt = 0; pt < 4; pt++) {
                    f32x4 rc = {0.f, 0.f, 0.f, 0.f};
                    rc = __builtin_amdgcn_mfma_f32_16x16x32_bf16(ff[mt], pf[pt], rc, 0, 0, 0);
                    #pragma unroll
                    for (int r = 0; r < 4; r++)
                        red[w][(q4 * 4 + r) * 64 + pt * 16 + col] = rc[r];
                }
            }
            __syncthreads();
            {   // block partial (1024 elems this mt) -> packed bf16 pairs
                float s0 = 0.f, s1 = 0.f;
                #pragma unroll
                for (int w8 = 0; w8 < 8; w8++) {
                    s0 += red[w8][2 * t];
                    s1 += red[w8][2 * t + 1];
                }
                gstore32(&pslot[mt * 512 + t], pack2(s0, s1));
            }
            __syncthreads();
        }

        flagbar(flags, blk, (unsigned)(k + 1));

        // ========= redundant reduce: f elems 4t..4t+3 = -sum over 64 slots =========
        float fv[4];
        {
            const u64t* pb = (const u64t*)(pbuf + (size_t)par * (NBLK * 1024));
            float s0 = 0.f, s1 = 0.f, s2 = 0.f, s3 = 0.f;
            #pragma unroll 8
            for (int s = 0; s < NBLK; s++) {
                u64t v = gload64(pb + (size_t)s * 512 + t);
                unsigned lo = (unsigned)v, hi = (unsigned)(v >> 32);
                s0 += __uint_as_float(lo << 16);
                s1 += __uint_as_float(lo & 0xffff0000u);
                s2 += __uint_as_float(hi << 16);
                s3 += __uint_as_float(hi & 0xffff0000u);
            }
            fv[0] = -s0; fv[1] = -s1; fv[2] = -s2; fv[3] = -s3;
        }

        // ================= phase B: BDF2 combine + solve =================
        {
            const int b = (4 * t) >> 6, p0 = (4 * t) & 63;
            #pragma unroll
            for (int jj = 0; jj < 4; jj++) {
                float f = fv[jj];
                int row = b * 68 + p0 + jj;
                float av = Ab[ia_cur][row];
                float rv = (k == 0) ? (av + DTC * f)
                                    : (4.f * av - Ab[ia_prev][row]
                                       + 4.f * DTC * f - 2.f * DTC * fprev[jj]);
                rbuf[row] = rv;
                fprev[jj] = f;
            }
        }
        __syncthreads();

        if (w < 2) {
            // a_next = cbase*r + r @ S^T (r hi/lo bf16; verified r4-r5)
            auto solve = [&](const bf16x8 (&S)[4][2], float cbase) {
                int m = w * 16 + nr;
                bf16x8 rhi[2], rlo[2];
                #pragma unroll
                for (int kt = 0; kt < 2; kt++) {
                    us8 hv, lv;
                    #pragma unroll
                    for (int j = 0; j < 8; j++) {
                        float x = rbuf[m * 68 + kt * 32 + c0 + j];
                        unsigned short h = f2bf(x);
                        hv[j] = h;
                        lv[j] = f2bf(x - bf2f(h));
                    }
                    rhi[kt] = __builtin_bit_cast(bf16x8, hv);
                    rlo[kt] = __builtin_bit_cast(bf16x8, lv);
                }
                int col = l & 15, q4 = l >> 4;
                #pragma unroll
                for (int pt = 0; pt < 4; pt++) {
                    f32x4 acc;
                    #pragma unroll
                    for (int r = 0; r < 4; r++)
                        acc[r] = rbuf[(w * 16 + q4 * 4 + r) * 68 + pt * 16 + col] * cbase;
                    #pragma unroll
                    for (int kt = 0; kt < 2; kt++) {
                        acc = __builtin_amdgcn_mfma_f32_16x16x32_bf16(rhi[kt], S[pt][kt], acc, 0, 0, 0);
                        acc = __builtin_amdgcn_mfma_f32_16x16x32_bf16(rlo[kt], S[pt][kt], acc, 0, 0, 0);
                    }
                    #pragma unroll
                    for (int r = 0; r < 4; r++)
                        Ab[ia_next][(w * 16 + q4 * 4 + r) * 68 + pt * 16 + col] = acc[r];
                }
            };
            if (k == 0) {
                bf16x8 s1f[4][2];               // S1 = inv1 - I, built once
                #pragma unroll
                for (int pt = 0; pt < 4; pt++)
                    #pragma unroll
                    for (int kt = 0; kt < 2; kt++) {
                        int p = pt * 16 + nr;
                        const float* s = inv1 + (size_t)p * 64 + kt * 32 + c0;
                        us8 o;
                        #pragma unroll
                        for (int j = 0; j < 8; j++) {
                            float v = s[j] - ((p == kt * 32 + c0 + j) ? 1.0f : 0.0f);
                            o[j] = f2bf(v);
                        }
                        s1f[pt][kt] = __builtin_bit_cast(bf16x8, o);
                    }
                solve(s1f, 1.0f);
            } else {
                solve(sf, 1.0f / 3.0f);
            }
        }
        __syncthreads();

        if (k == NSTEP - 1 && blk == 0) {
            for (int i = t; i < 2048; i += 512)
                out[i] = (Ab[ia_next][(i >> 6) * 68 + (i & 63)] - state[i]) * INV_DT_SKIP;
        }

        int tmp = ia_prev; ia_prev = ia_cur; ia_cur = ia_next; ia_next = tmp;
    }
}

// ---------------------------------------------------------------------------
extern "C" void kernel_launch(void* const* d_in, const int* in_sizes, int n_in,
                              void* d_out, int out_size, void* d_ws, size_t ws_size,
                              hipStream_t stream) {
    const float* state = (const float*)d_in[0];   // (32, 64)
    const float* Ap    = (const float*)d_in[1];   // (64, 64)
    const float* Wu    = (const float*)d_in[2];   // (32000, 64)
    const float* Wv    = (const float*)d_in[3];   // (32000, 64)
    const float* Pp    = (const float*)d_in[4];   // (64, 16000)
    float* out = (float*)d_out;
    float* ws  = (float*)d_ws;

    float* inv1 = ws;                               // 4096 floats
    float* inv2 = ws + 4096;                        // 4096 floats
    unsigned* flags = (unsigned*)(ws + 8192);       // 64 u32 (+pad to 64 fl)
    unsigned* pbuf  = (unsigned*)(ws + 8192 + 64);  // 2 x 64 x 1024 u32

    hipLaunchKernelGGL(kzero, dim3(1), dim3(64), 0, stream, flags);
    hipLaunchKernelGGL(kinv, dim3(2), dim3(256), 0, stream, Ap, inv1, inv2);
    hipLaunchKernelGGL(kmain, dim3(NBLK), dim3(512), 0, stream,
                       state, Wu, Wv, Pp, inv1, inv2, pbuf, flags, out);
}

// Round 7
// 613.138 us; speedup vs baseline: 1.0701x; 1.0701x over previous
//
#include <hip/hip_runtime.h>

#define DTC 0.02f
#define INV_DT_SKIP 2.5f            // 1/(0.02*20)
#define NBLK 32
#define NSTEP 50

typedef __attribute__((ext_vector_type(8))) __bf16 bf16x8;
typedef __attribute__((ext_vector_type(4))) float f32x4;
typedef __attribute__((ext_vector_type(8))) unsigned short us8;
typedef unsigned long long u64t;

__device__ inline unsigned short f2bf(float x) {        // RNE fp32->bf16
    unsigned u = __float_as_uint(x);
    unsigned r = u + 0x7FFF + ((u >> 16) & 1u);
    return (unsigned short)(r >> 16);
}
__device__ inline float bf2f(unsigned short h) {
    return __uint_as_float(((unsigned)h) << 16);
}
__device__ inline unsigned pack2(float a, float b) {
    return (unsigned)f2bf(a) | ((unsigned)f2bf(b) << 16);
}
// Agent-scoped (cross-XCD coherent) accesses for all cross-block data.
__device__ inline void gstore32(unsigned* p, unsigned v) {
    __hip_atomic_store(p, v, __ATOMIC_RELAXED, __HIP_MEMORY_SCOPE_AGENT);
}
__device__ inline u64t gload64(const u64t* p) {
    return __hip_atomic_load(p, __ATOMIC_RELAXED, __HIP_MEMORY_SCOPE_AGENT);
}

// ---------------------------------------------------------------------------
// Neumann inverses (verified rounds 1-6). inv1 = (I-dt*Ap)^-1,
// inv2 = (3I-2dt*Ap)^-1.
// ---------------------------------------------------------------------------
__global__ __launch_bounds__(256) void kinv(const float* __restrict__ Ap,
                                            float* __restrict__ inv1,
                                            float* __restrict__ inv2) {
    const int t = threadIdx.x;
    const float coef  = (blockIdx.x == 0) ? DTC : (2.0f * DTC / 3.0f);
    const float scale = (blockIdx.x == 0) ? 1.0f : (1.0f / 3.0f);
    float* outp = (blockIdx.x == 0) ? inv1 : inv2;

    __shared__ float ET[64 * 68];
    __shared__ float XA[64 * 68];
    __shared__ float XB[64 * 68];

    for (int idx = t; idx < 4096; idx += 256) {
        int r = idx >> 6, c = idx & 63;
        float e = coef * Ap[idx];
        ET[c * 68 + r] = e;
        XA[r * 68 + c] = ((r == c) ? 1.0f : 0.0f) + e;
    }
    __syncthreads();

    const int rr = (t >> 4) << 2;
    const int cc = (t & 15) << 2;
    float* bufs[2] = {XA, XB};
    for (int it = 0; it < 3; it++) {
        const float* Xin = bufs[it & 1];
        float* Xout = bufs[(it + 1) & 1];
        float acc[4][4];
        #pragma unroll
        for (int i = 0; i < 4; i++)
            #pragma unroll
            for (int j = 0; j < 4; j++)
                acc[i][j] = ((rr + i) == (cc + j)) ? 1.0f : 0.0f;
        for (int k = 0; k < 64; k++) {
            float4 e4 = *(const float4*)&ET[k * 68 + rr];
            float4 x4 = *(const float4*)&Xin[k * 68 + cc];
            float ev[4] = {e4.x, e4.y, e4.z, e4.w};
            float xv[4] = {x4.x, x4.y, x4.z, x4.w};
            #pragma unroll
            for (int i = 0; i < 4; i++)
                #pragma unroll
                for (int j = 0; j < 4; j++)
                    acc[i][j] += ev[i] * xv[j];
        }
        __syncthreads();
        #pragma unroll
        for (int i = 0; i < 4; i++)
            #pragma unroll
            for (int j = 0; j < 4; j++)
                Xout[(rr + i) * 68 + cc + j] = acc[i][j];
        __syncthreads();
    }
    const float* Xf = bufs[1];
    for (int idx = t; idx < 4096; idx += 256) {
        int r = idx >> 6, c = idx & 63;
        outp[idx] = scale * Xf[r * 68 + c];
    }
}

__global__ void kzero(unsigned* __restrict__ flags) {
    if (threadIdx.x < NBLK) flags[threadIdx.x] = 0u;
}

// ---------------------------------------------------------------------------
// Parallel-flag grid barrier (monotone, no reset). Arrival = one agent store;
// detection = 64-lane coalesced load of the 32 flags (duplicated) + __all.
// __syncthreads drains each wave's outstanding stores before the leader's
// RELEASE flag. 32 blocks trivially co-resident on 256 CUs.
// ---------------------------------------------------------------------------
__device__ inline void flagbar(unsigned* flags, int blk, unsigned target) {
    __syncthreads();
    if (threadIdx.x < 64) {
        if (threadIdx.x == 0)
            __hip_atomic_store(&flags[blk], target, __ATOMIC_RELEASE, __HIP_MEMORY_SCOPE_AGENT);
        for (;;) {
            unsigned v = __hip_atomic_load(&flags[threadIdx.x & (NBLK - 1)], __ATOMIC_ACQUIRE,
                                           __HIP_MEMORY_SCOPE_AGENT);
            if (__all(v >= target)) break;
            __builtin_amdgcn_s_sleep(2);
        }
    }
    __syncthreads();
}

// ---------------------------------------------------------------------------
// Persistent kernel, 32 blocks, ONE barrier per step.
// Wave gw = blk*8+w owns chunks 2gw, 2gw+1 (gw<250; both same net). All W/P
// fragments register-resident (wf 128 + pf 32 VGPRs). Per step:
//   Phase A (mt outer, chunk inner): z = a@W^T hi/lo bf16 MFMA, f=u*dx+v*dy,
//   intra-wave LDS C->A relayout (no block sync needed), proj MFMA
//   accumulating over both chunks -> red -> block reduce -> bf16-packed
//   slot (parity double-buffered). flagbar. Redundant reduce: every block
//   sums all 32 slots (coalesced u64 agent loads) -> f in regs (4/thread,
//   f_prev in regs). BDF2 r -> LDS; solve a_next = cb*r + r@S^T distributed
//   over all 8 waves (wave -> one (mt,pt) 16x16 tile). Block 0 writes out.
// pbuf parity WAR safety: all blocks passed barrier k ==> all finished step
// k-1's reduce, which last read parity(k+1).
// ---------------------------------------------------------------------------
__global__ __launch_bounds__(512, 2)
void kmain(const float* __restrict__ state,
           const float* __restrict__ Wu,
           const float* __restrict__ Wv,
           const float* __restrict__ Pp,
           const float* __restrict__ inv1,
           const float* __restrict__ inv2,
           unsigned* __restrict__ pbuf,     // 2 parities x 32 slots x 1024 u32
           unsigned* __restrict__ flags,    // NBLK flag words
           float* __restrict__ out) {
    const int t = threadIdx.x;
    const int l = t & 63;
    const int w = t >> 6;                 // wave 0..7
    const int blk = blockIdx.x;
    const int gw = blk * 8 + w;           // 0..255
    const bool active = (gw < 250);       // waves 250..255 idle in phase A

    __shared__ float Ab[3][2176];         // a triple buffer, 32 rows x 68
    __shared__ float fb[8][16][36];       // per-wave f tile (K=32 + pad)
    __shared__ float red[8][1024];        // per-wave proj partials (16b x 64p)
    __shared__ float rbuf[32 * 68];       // r, padded stride 68

    for (int i = t; i < 2048; i += 512) Ab[0][(i >> 6) * 68 + (i & 63)] = state[i];
    if (!active)                           // idle waves' red stays zero forever
        for (int i = l; i < 1024; i += 64) red[w][i] = 0.f;

    const int nr = l & 15;
    const int c0 = (l >> 4) << 3;
    const int cA = gw * 2;                 // chunk ids (cA,cA+1), same net
    const float* W = (cA < 250) ? Wu : Wv;
    const int glA = ((cA < 250) ? cA : cA - 250) * 32;

    // ---- register-resident fragments ----
    bf16x8 wf[2][2][4][2], pf[2][4], sfw[2];
    if (active) {
        #pragma unroll
        for (int ch = 0; ch < 2; ch++)
            #pragma unroll
            for (int th = 0; th < 2; th++)
                #pragma unroll
                for (int rb = 0; rb < 4; rb++)
                    #pragma unroll
                    for (int kt = 0; kt < 2; kt++) {
                        const float* s = W + (size_t)(rb * 8000 + glA + ch * 32 + th * 16 + nr) * 64
                                           + kt * 32 + c0;
                        us8 o;
                        #pragma unroll
                        for (int j = 0; j < 8; j++) o[j] = f2bf(s[j]);
                        wf[ch][th][rb][kt] = __builtin_bit_cast(bf16x8, o);
                    }
        #pragma unroll
        for (int ch = 0; ch < 2; ch++)
            #pragma unroll
            for (int pt = 0; pt < 4; pt++) {
                const float* s = Pp + (size_t)(pt * 16 + nr) * 16000 + (cA + ch) * 32 + c0;
                us8 o;
                #pragma unroll
                for (int j = 0; j < 8; j++) o[j] = f2bf(s[j]);
                pf[ch][pt] = __builtin_bit_cast(bf16x8, o);
            }
    }
    {   // wave's solve tile: mtS = w>>2, ptS = w&3 ; S = inv2 - I/3
        const int ptS = w & 3;
        #pragma unroll
        for (int kt = 0; kt < 2; kt++) {
            int p = ptS * 16 + nr;
            const float* s = inv2 + (size_t)p * 64 + kt * 32 + c0;
            us8 o;
            #pragma unroll
            for (int j = 0; j < 8; j++) {
                float v = s[j] - ((p == kt * 32 + c0 + j) ? (1.0f / 3.0f) : 0.0f);
                o[j] = f2bf(v);
            }
            sfw[kt] = __builtin_bit_cast(bf16x8, o);
        }
    }
    __syncthreads();

    int ia_prev = 2, ia_cur = 0, ia_next = 1;
    float fprev[4];                       // f_prev for elems 4t..4t+3

    for (int k = 0; k < NSTEP; k++) {
        const int par = k & 1;
        unsigned* pslot = pbuf + (size_t)par * (NBLK * 1024) + blk * 1024;

        // ================= phase A: rhs partials =================
        #pragma unroll
        for (int mt = 0; mt < 2; mt++) {
            if (active) {
                bf16x8 ahi[2], alo[2];
                {
                    const float* ac = Ab[ia_cur];
                    #pragma unroll
                    for (int kt = 0; kt < 2; kt++) {
                        us8 hv, lv;
                        #pragma unroll
                        for (int j = 0; j < 8; j++) {
                            float x = ac[(mt * 16 + nr) * 68 + kt * 32 + c0 + j];
                            unsigned short h = f2bf(x);
                            hv[j] = h;
                            lv[j] = f2bf(x - bf2f(h));
                        }
                        ahi[kt] = __builtin_bit_cast(bf16x8, hv);
                        alo[kt] = __builtin_bit_cast(bf16x8, lv);
                    }
                }
                const int col = l & 15, q4 = l >> 4;
                f32x4 racc[4] = {{0.f,0.f,0.f,0.f},{0.f,0.f,0.f,0.f},
                                 {0.f,0.f,0.f,0.f},{0.f,0.f,0.f,0.f}};
                #pragma unroll
                for (int ch = 0; ch < 2; ch++) {
                    #pragma unroll
                    for (int th = 0; th < 2; th++) {
                        f32x4 z[4];
                        #pragma unroll
                        for (int rb = 0; rb < 4; rb++) {
                            f32x4 acc = {0.f, 0.f, 0.f, 0.f};
                            #pragma unroll
                            for (int kt = 0; kt < 2; kt++) {
                                acc = __builtin_amdgcn_mfma_f32_16x16x32_bf16(ahi[kt], wf[ch][th][rb][kt], acc, 0, 0, 0);
                                acc = __builtin_amdgcn_mfma_f32_16x16x32_bf16(alo[kt], wf[ch][th][rb][kt], acc, 0, 0, 0);
                            }
                            z[rb] = acc;
                        }
                        #pragma unroll
                        for (int r = 0; r < 4; r++) {
                            float f = z[0][r] * z[2][r] + z[1][r] * z[3][r];
                            fb[w][q4 * 4 + r][th * 16 + col] = f;   // intra-wave only
                        }
                    }
                    bf16x8 ff;
                    {
                        us8 fv8;
                        #pragma unroll
                        for (int j = 0; j < 8; j++) fv8[j] = f2bf(fb[w][nr][c0 + j]);
                        ff = __builtin_bit_cast(bf16x8, fv8);
                    }
                    #pragma unroll
                    for (int pt = 0; pt < 4; pt++)
                        racc[pt] = __builtin_amdgcn_mfma_f32_16x16x32_bf16(ff, pf[ch][pt], racc[pt], 0, 0, 0);
                }
                #pragma unroll
                for (int pt = 0; pt < 4; pt++)
                    #pragma unroll
                    for (int r = 0; r < 4; r++)
                        red[w][(q4 * 4 + r) * 64 + pt * 16 + col] = racc[pt][r];
            }
            __syncthreads();
            {   // block partial (1024 elems this mt) -> packed bf16 pairs
                float s0 = 0.f, s1 = 0.f;
                #pragma unroll
                for (int w8 = 0; w8 < 8; w8++) {
                    s0 += red[w8][2 * t];
                    s1 += red[w8][2 * t + 1];
                }
                gstore32(&pslot[mt * 512 + t], pack2(s0, s1));
            }
            __syncthreads();               // WAR before next mt rewrites red
        }

        flagbar(flags, blk, (unsigned)(k + 1));

        // ========= redundant reduce: f elems 4t..4t+3 = -sum over 32 slots =========
        float fv[4];
        {
            const u64t* pb = (const u64t*)(pbuf + (size_t)par * (NBLK * 1024));
            float s0 = 0.f, s1 = 0.f, s2 = 0.f, s3 = 0.f;
            #pragma unroll
            for (int s = 0; s < NBLK; s++) {
                u64t v = gload64(pb + (size_t)s * 512 + t);
                unsigned lo = (unsigned)v, hi = (unsigned)(v >> 32);
                s0 += __uint_as_float(lo << 16);
                s1 += __uint_as_float(lo & 0xffff0000u);
                s2 += __uint_as_float(hi << 16);
                s3 += __uint_as_float(hi & 0xffff0000u);
            }
            fv[0] = -s0; fv[1] = -s1; fv[2] = -s2; fv[3] = -s3;
        }

        // ================= phase B: BDF2 combine + distributed solve =================
        {
            const int b = (4 * t) >> 6, p0 = (4 * t) & 63;
            #pragma unroll
            for (int jj = 0; jj < 4; jj++) {
                float f = fv[jj];
                int row = b * 68 + p0 + jj;
                float av = Ab[ia_cur][row];
                float rv = (k == 0) ? (av + DTC * f)
                                    : (4.f * av - Ab[ia_prev][row]
                                       + 4.f * DTC * f - 2.f * DTC * fprev[jj]);
                rbuf[row] = rv;
                fprev[jj] = f;
            }
        }
        __syncthreads();

        {   // wave (mtS = w>>2, ptS = w&3): a_next tile = cb*r + (r @ S^T) tile
            const int mtS = w >> 2, ptS = w & 3;
            const int col = l & 15, q4 = l >> 4;
            bf16x8 S0, S1;
            float cb;
            if (k == 0) {                   // S1 = inv1 - I, cb = 1
                #pragma unroll
                for (int kt = 0; kt < 2; kt++) {
                    int p = ptS * 16 + nr;
                    const float* s = inv1 + (size_t)p * 64 + kt * 32 + c0;
                    us8 o;
                    #pragma unroll
                    for (int j = 0; j < 8; j++) {
                        float v = s[j] - ((p == kt * 32 + c0 + j) ? 1.0f : 0.0f);
                        o[j] = f2bf(v);
                    }
                    if (kt == 0) S0 = __builtin_bit_cast(bf16x8, o);
                    else         S1 = __builtin_bit_cast(bf16x8, o);
                }
                cb = 1.0f;
            } else {
                S0 = sfw[0]; S1 = sfw[1];
                cb = 1.0f / 3.0f;
            }
            bf16x8 rhi[2], rlo[2];
            #pragma unroll
            for (int kt = 0; kt < 2; kt++) {
                us8 hv, lv;
                #pragma unroll
                for (int j = 0; j < 8; j++) {
                    float x = rbuf[(mtS * 16 + nr) * 68 + kt * 32 + c0 + j];
                    unsigned short h = f2bf(x);
                    hv[j] = h;
                    lv[j] = f2bf(x - bf2f(h));
                }
                rhi[kt] = __builtin_bit_cast(bf16x8, hv);
                rlo[kt] = __builtin_bit_cast(bf16x8, lv);
            }
            f32x4 acc;
            #pragma unroll
            for (int r = 0; r < 4; r++)
                acc[r] = rbuf[(mtS * 16 + q4 * 4 + r) * 68 + ptS * 16 + col] * cb;
            acc = __builtin_amdgcn_mfma_f32_16x16x32_bf16(rhi[0], S0, acc, 0, 0, 0);
            acc = __builtin_amdgcn_mfma_f32_16x16x32_bf16(rlo[0], S0, acc, 0, 0, 0);
            acc = __builtin_amdgcn_mfma_f32_16x16x32_bf16(rhi[1], S1, acc, 0, 0, 0);
            acc = __builtin_amdgcn_mfma_f32_16x16x32_bf16(rlo[1], S1, acc, 0, 0, 0);
            #pragma unroll
            for (int r = 0; r < 4; r++)
                Ab[ia_next][(mtS * 16 + q4 * 4 + r) * 68 + ptS * 16 + col] = acc[r];
        }
        __syncthreads();

        if (k == NSTEP - 1 && blk == 0) {
            for (int i = t; i < 2048; i += 512)
                out[i] = (Ab[ia_next][(i >> 6) * 68 + (i & 63)] - state[i]) * INV_DT_SKIP;
        }

        int tmp = ia_prev; ia_prev = ia_cur; ia_cur = ia_next; ia_next = tmp;
    }
}

// ---------------------------------------------------------------------------
extern "C" void kernel_launch(void* const* d_in, const int* in_sizes, int n_in,
                              void* d_out, int out_size, void* d_ws, size_t ws_size,
                              hipStream_t stream) {
    const float* state = (const float*)d_in[0];   // (32, 64)
    const float* Ap    = (const float*)d_in[1];   // (64, 64)
    const float* Wu    = (const float*)d_in[2];   // (32000, 64)
    const float* Wv    = (const float*)d_in[3];   // (32000, 64)
    const float* Pp    = (const float*)d_in[4];   // (64, 16000)
    float* out = (float*)d_out;
    float* ws  = (float*)d_ws;

    float* inv1 = ws;                               // 4096 floats
    float* inv2 = ws + 4096;                        // 4096 floats
    unsigned* flags = (unsigned*)(ws + 8192);       // NBLK u32 (pad to 64)
    unsigned* pbuf  = (unsigned*)(ws + 8192 + 64);  // 2 x 32 x 1024 u32

    hipLaunchKernelGGL(kzero, dim3(1), dim3(64), 0, stream, flags);
    hipLaunchKernelGGL(kinv, dim3(2), dim3(256), 0, stream, Ap, inv1, inv2);
    hipLaunchKernelGGL(kmain, dim3(NBLK), dim3(512), 0, stream,
                       state, Wu, Wv, Pp, inv1, inv2, pbuf, flags, out);
}

// Round 8
// 544.877 us; speedup vs baseline: 1.2041x; 1.1253x over previous
//
#include <hip/hip_runtime.h>

#define DTC 0.02f
#define INV_DT_SKIP 2.5f            // 1/(0.02*20)
#define NBLK 32
#define NSTEP 50

typedef __attribute__((ext_vector_type(8))) __bf16 bf16x8;
typedef __attribute__((ext_vector_type(4))) float f32x4;
typedef __attribute__((ext_vector_type(8))) unsigned short us8;
typedef unsigned long long u64t;

__device__ inline unsigned short f2bf(float x) {        // RNE fp32->bf16
    unsigned u = __float_as_uint(x);
    unsigned r = u + 0x7FFF + ((u >> 16) & 1u);
    return (unsigned short)(r >> 16);
}
__device__ inline float bf2f(unsigned short h) {
    return __uint_as_float(((unsigned)h) << 16);
}
__device__ inline unsigned pack2(float a, float b) {
    return (unsigned)f2bf(a) | ((unsigned)f2bf(b) << 16);
}
// Agent-scoped (cross-XCD, coherence-point) RELAXED accesses. Ordering is
// carried by the vmcnt(0) drain inside __syncthreads before flag publish,
// plus a compiler barrier after poll success (stops load hoisting).
__device__ inline void gstore32(unsigned* p, unsigned v) {
    __hip_atomic_store(p, v, __ATOMIC_RELAXED, __HIP_MEMORY_SCOPE_AGENT);
}
__device__ inline unsigned gload32(const unsigned* p) {
    return __hip_atomic_load(p, __ATOMIC_RELAXED, __HIP_MEMORY_SCOPE_AGENT);
}
__device__ inline u64t gload64(const u64t* p) {
    return __hip_atomic_load(p, __ATOMIC_RELAXED, __HIP_MEMORY_SCOPE_AGENT);
}
// Pin a 16B fragment into VGPRs: opaque def prevents the allocator from
// rematerializing the global load + bf16 conversion every loop iteration.
#define PINV(x) asm volatile("" : "+v"(x))

// ---------------------------------------------------------------------------
// Neumann inverses (verified rounds 1-7). inv1 = (I-dt*Ap)^-1,
// inv2 = (3I-2dt*Ap)^-1.
// ---------------------------------------------------------------------------
__global__ __launch_bounds__(256) void kinv(const float* __restrict__ Ap,
                                            float* __restrict__ inv1,
                                            float* __restrict__ inv2) {
    const int t = threadIdx.x;
    const float coef  = (blockIdx.x == 0) ? DTC : (2.0f * DTC / 3.0f);
    const float scale = (blockIdx.x == 0) ? 1.0f : (1.0f / 3.0f);
    float* outp = (blockIdx.x == 0) ? inv1 : inv2;

    __shared__ float ET[64 * 68];
    __shared__ float XA[64 * 68];
    __shared__ float XB[64 * 68];

    for (int idx = t; idx < 4096; idx += 256) {
        int r = idx >> 6, c = idx & 63;
        float e = coef * Ap[idx];
        ET[c * 68 + r] = e;
        XA[r * 68 + c] = ((r == c) ? 1.0f : 0.0f) + e;
    }
    __syncthreads();

    const int rr = (t >> 4) << 2;
    const int cc = (t & 15) << 2;
    float* bufs[2] = {XA, XB};
    for (int it = 0; it < 3; it++) {
        const float* Xin = bufs[it & 1];
        float* Xout = bufs[(it + 1) & 1];
        float acc[4][4];
        #pragma unroll
        for (int i = 0; i < 4; i++)
            #pragma unroll
            for (int j = 0; j < 4; j++)
                acc[i][j] = ((rr + i) == (cc + j)) ? 1.0f : 0.0f;
        for (int k = 0; k < 64; k++) {
            float4 e4 = *(const float4*)&ET[k * 68 + rr];
            float4 x4 = *(const float4*)&Xin[k * 68 + cc];
            float ev[4] = {e4.x, e4.y, e4.z, e4.w};
            float xv[4] = {x4.x, x4.y, x4.z, x4.w};
            #pragma unroll
            for (int i = 0; i < 4; i++)
                #pragma unroll
                for (int j = 0; j < 4; j++)
                    acc[i][j] += ev[i] * xv[j];
        }
        __syncthreads();
        #pragma unroll
        for (int i = 0; i < 4; i++)
            #pragma unroll
            for (int j = 0; j < 4; j++)
                Xout[(rr + i) * 68 + cc + j] = acc[i][j];
        __syncthreads();
    }
    const float* Xf = bufs[1];
    for (int idx = t; idx < 4096; idx += 256) {
        int r = idx >> 6, c = idx & 63;
        outp[idx] = scale * Xf[r * 68 + c];
    }
}

__global__ void kzero(unsigned* __restrict__ flags) {
    if (threadIdx.x < NBLK) flags[threadIdx.x] = 0u;
}

// ---------------------------------------------------------------------------
// Persistent kernel, 32 blocks, one flag-barrier per step, all-RELAXED.
// Wave gw = blk*8+w owns chunks 2gw, 2gw+1 (gw<250). W/P/S fragments pinned
// in VGPRs (PINV) for the whole kernel. Per step:
//   Phase A: z = a@W^T hi/lo bf16 MFMA, f=u*dx+v*dy, intra-wave LDS C->A
//   relayout, proj MFMA (both chunks, both mt) -> red2 -> sync -> block
//   reduce -> bf16-packed slot (parity double-buffered) -> sync (drains
//   stores) -> flag publish; ALL waves poll all 32 flags (no post-poll
//   sync) -> gather 32 slots (coalesced u64 agent loads) -> f in regs ->
//   BDF2 r -> LDS -> sync -> distributed solve (wave -> one (mt,pt) tile)
//   -> sync. Block 0 writes out at last step.
// pbuf parity WAR safety: observing flag(k+1) from every block implies that
// block finished its step-k gather (program order + vmcnt drain), which
// last read parity(k+1).
// ---------------------------------------------------------------------------
__global__ __launch_bounds__(512, 2)
void kmain(const float* __restrict__ state,
           const float* __restrict__ Wu,
           const float* __restrict__ Wv,
           const float* __restrict__ Pp,
           const float* __restrict__ inv1,
           const float* __restrict__ inv2,
           unsigned* __restrict__ pbuf,     // 2 parities x 32 slots x 1024 u32
           unsigned* __restrict__ flags,    // NBLK flag words
           float* __restrict__ out) {
    const int t = threadIdx.x;
    const int l = t & 63;
    const int w = t >> 6;                 // wave 0..7
    const int blk = blockIdx.x;
    const int gw = blk * 8 + w;           // 0..255
    const bool active = (gw < 250);       // waves 250..255 idle in phase A

    __shared__ float Ab[3][2176];         // a triple buffer, 32 rows x 68
    __shared__ float fb[8][16][36];       // per-wave f tile (K=32 + pad)
    __shared__ float red2[2][8][1024];    // per-mt, per-wave proj partials
    __shared__ float rbuf[32 * 68];       // r, padded stride 68

    for (int i = t; i < 2048; i += 512) Ab[0][(i >> 6) * 68 + (i & 63)] = state[i];
    if (!active) {                        // idle waves' red2 stays zero forever
        for (int i = l; i < 1024; i += 64) { red2[0][w][i] = 0.f; red2[1][w][i] = 0.f; }
    }

    const int nr = l & 15;
    const int c0 = (l >> 4) << 3;
    const int cA = gw * 2;                 // chunk ids (cA,cA+1), same net
    const float* W = (cA < 250) ? Wu : Wv;
    const int glA = ((cA < 250) ? cA : cA - 250) * 32;

    // ---- persistent fragments, pinned into VGPRs ----
    bf16x8 wf[2][2][4][2], pf[2][4], sfw[2];
    if (active) {
        #pragma unroll
        for (int ch = 0; ch < 2; ch++)
            #pragma unroll
            for (int th = 0; th < 2; th++)
                #pragma unroll
                for (int rb = 0; rb < 4; rb++)
                    #pragma unroll
                    for (int kt = 0; kt < 2; kt++) {
                        const float* s = W + (size_t)(rb * 8000 + glA + ch * 32 + th * 16 + nr) * 64
                                           + kt * 32 + c0;
                        us8 o;
                        #pragma unroll
                        for (int j = 0; j < 8; j++) o[j] = f2bf(s[j]);
                        wf[ch][th][rb][kt] = __builtin_bit_cast(bf16x8, o);
                    }
        #pragma unroll
        for (int ch = 0; ch < 2; ch++)
            #pragma unroll
            for (int pt = 0; pt < 4; pt++) {
                const float* s = Pp + (size_t)(pt * 16 + nr) * 16000 + (cA + ch) * 32 + c0;
                us8 o;
                #pragma unroll
                for (int j = 0; j < 8; j++) o[j] = f2bf(s[j]);
                pf[ch][pt] = __builtin_bit_cast(bf16x8, o);
            }
    }
    {   // wave's solve tile: mtS = w>>2, ptS = w&3 ; S = inv2 - I/3
        const int ptS = w & 3;
        #pragma unroll
        for (int kt = 0; kt < 2; kt++) {
            int p = ptS * 16 + nr;
            const float* s = inv2 + (size_t)p * 64 + kt * 32 + c0;
            us8 o;
            #pragma unroll
            for (int j = 0; j < 8; j++) {
                float v = s[j] - ((p == kt * 32 + c0 + j) ? (1.0f / 3.0f) : 0.0f);
                o[j] = f2bf(v);
            }
            sfw[kt] = __builtin_bit_cast(bf16x8, o);
        }
    }
    // pin everything (opaque defs -> no rematerialization inside the loop)
    #pragma unroll
    for (int ch = 0; ch < 2; ch++) {
        #pragma unroll
        for (int th = 0; th < 2; th++)
            #pragma unroll
            for (int rb = 0; rb < 4; rb++)
                #pragma unroll
                for (int kt = 0; kt < 2; kt++) PINV(wf[ch][th][rb][kt]);
        #pragma unroll
        for (int pt = 0; pt < 4; pt++) PINV(pf[ch][pt]);
    }
    PINV(sfw[0]); PINV(sfw[1]);
    __syncthreads();

    int ia_prev = 2, ia_cur = 0, ia_next = 1;
    float fprev[4];                       // f_prev for elems 4t..4t+3

    for (int k = 0; k < NSTEP; k++) {
        const int par = k & 1;
        unsigned* pslot = pbuf + (size_t)par * (NBLK * 1024) + blk * 1024;

        // ================= phase A: rhs partials =================
        if (active) {
            const int col = l & 15, q4 = l >> 4;
            #pragma unroll
            for (int mt = 0; mt < 2; mt++) {
                bf16x8 ahi[2], alo[2];
                {
                    const float* ac = Ab[ia_cur];
                    #pragma unroll
                    for (int kt = 0; kt < 2; kt++) {
                        us8 hv, lv;
                        #pragma unroll
                        for (int j = 0; j < 8; j++) {
                            float x = ac[(mt * 16 + nr) * 68 + kt * 32 + c0 + j];
                            unsigned short h = f2bf(x);
                            hv[j] = h;
                            lv[j] = f2bf(x - bf2f(h));
                        }
                        ahi[kt] = __builtin_bit_cast(bf16x8, hv);
                        alo[kt] = __builtin_bit_cast(bf16x8, lv);
                    }
                }
                f32x4 racc[4] = {{0.f,0.f,0.f,0.f},{0.f,0.f,0.f,0.f},
                                 {0.f,0.f,0.f,0.f},{0.f,0.f,0.f,0.f}};
                #pragma unroll
                for (int ch = 0; ch < 2; ch++) {
                    #pragma unroll
                    for (int th = 0; th < 2; th++) {
                        f32x4 z[4];
                        #pragma unroll
                        for (int rb = 0; rb < 4; rb++) {
                            f32x4 acc = {0.f, 0.f, 0.f, 0.f};
                            #pragma unroll
                            for (int kt = 0; kt < 2; kt++) {
                                acc = __builtin_amdgcn_mfma_f32_16x16x32_bf16(ahi[kt], wf[ch][th][rb][kt], acc, 0, 0, 0);
                                acc = __builtin_amdgcn_mfma_f32_16x16x32_bf16(alo[kt], wf[ch][th][rb][kt], acc, 0, 0, 0);
                            }
                            z[rb] = acc;
                        }
                        #pragma unroll
                        for (int r = 0; r < 4; r++) {
                            float f = z[0][r] * z[2][r] + z[1][r] * z[3][r];
                            fb[w][q4 * 4 + r][th * 16 + col] = f;   // intra-wave only
                        }
                    }
                    bf16x8 ff;
                    {
                        us8 fv8;
                        #pragma unroll
                        for (int j = 0; j < 8; j++) fv8[j] = f2bf(fb[w][nr][c0 + j]);
                        ff = __builtin_bit_cast(bf16x8, fv8);
                    }
                    #pragma unroll
                    for (int pt = 0; pt < 4; pt++)
                        racc[pt] = __builtin_amdgcn_mfma_f32_16x16x32_bf16(ff, pf[ch][pt], racc[pt], 0, 0, 0);
                }
                #pragma unroll
                for (int pt = 0; pt < 4; pt++)
                    #pragma unroll
                    for (int r = 0; r < 4; r++)
                        red2[mt][w][(q4 * 4 + r) * 64 + pt * 16 + col] = racc[pt][r];
            }
        }
        __syncthreads();

        // block partial (2048 elems) -> packed bf16 pairs, one slot
        #pragma unroll
        for (int mt = 0; mt < 2; mt++) {
            float s0 = 0.f, s1 = 0.f;
            #pragma unroll
            for (int w8 = 0; w8 < 8; w8++) {
                s0 += red2[mt][w8][2 * t];
                s1 += red2[mt][w8][2 * t + 1];
            }
            gstore32(&pslot[mt * 512 + t], pack2(s0, s1));
        }
        __syncthreads();                       // drains ALL waves' stores (vmcnt 0)

        // flag publish + all-wave poll (no post-poll sync needed)
        if (t == 0) gstore32(&flags[blk], (unsigned)(k + 1));
        {
            const unsigned target = (unsigned)(k + 1);
            for (;;) {
                unsigned v = gload32(&flags[l & (NBLK - 1)]);
                if (__all(v >= target)) break;
                __builtin_amdgcn_s_sleep(1);
            }
            asm volatile("" ::: "memory");     // keep gather below the poll
        }

        // ========= redundant reduce: f elems 4t..4t+3 = -sum over 32 slots =========
        float fv[4];
        {
            const u64t* pb = (const u64t*)(pbuf + (size_t)par * (NBLK * 1024));
            float s0 = 0.f, s1 = 0.f, s2 = 0.f, s3 = 0.f;
            #pragma unroll
            for (int s = 0; s < NBLK; s++) {
                u64t v = gload64(pb + (size_t)s * 512 + t);
                unsigned lo = (unsigned)v, hi = (unsigned)(v >> 32);
                s0 += __uint_as_float(lo << 16);
                s1 += __uint_as_float(lo & 0xffff0000u);
                s2 += __uint_as_float(hi << 16);
                s3 += __uint_as_float(hi & 0xffff0000u);
            }
            fv[0] = -s0; fv[1] = -s1; fv[2] = -s2; fv[3] = -s3;
        }

        // ================= phase B: BDF2 combine + distributed solve =================
        {
            const int b = (4 * t) >> 6, p0 = (4 * t) & 63;
            #pragma unroll
            for (int jj = 0; jj < 4; jj++) {
                float f = fv[jj];
                int row = b * 68 + p0 + jj;
                float av = Ab[ia_cur][row];
                float rv = (k == 0) ? (av + DTC * f)
                                    : (4.f * av - Ab[ia_prev][row]
                                       + 4.f * DTC * f - 2.f * DTC * fprev[jj]);
                rbuf[row] = rv;
                fprev[jj] = f;
            }
        }
        __syncthreads();

        {   // wave (mtS = w>>2, ptS = w&3): a_next tile = cb*r + (r @ S^T) tile
            const int mtS = w >> 2, ptS = w & 3;
            const int col = l & 15, q4 = l >> 4;
            bf16x8 S0, S1;
            float cb;
            if (k == 0) {                   // S1 = inv1 - I, cb = 1 (once)
                #pragma unroll
                for (int kt = 0; kt < 2; kt++) {
                    int p = ptS * 16 + nr;
                    const float* s = inv1 + (size_t)p * 64 + kt * 32 + c0;
                    us8 o;
                    #pragma unroll
                    for (int j = 0; j < 8; j++) {
                        float v = s[j] - ((p == kt * 32 + c0 + j) ? 1.0f : 0.0f);
                        o[j] = f2bf(v);
                    }
                    if (kt == 0) S0 = __builtin_bit_cast(bf16x8, o);
                    else         S1 = __builtin_bit_cast(bf16x8, o);
                }
                cb = 1.0f;
            } else {
                S0 = sfw[0]; S1 = sfw[1];
                cb = 1.0f / 3.0f;
            }
            bf16x8 rhi[2], rlo[2];
            #pragma unroll
            for (int kt = 0; kt < 2; kt++) {
                us8 hv, lv;
                #pragma unroll
                for (int j = 0; j < 8; j++) {
                    float x = rbuf[(mtS * 16 + nr) * 68 + kt * 32 + c0 + j];
                    unsigned short h = f2bf(x);
                    hv[j] = h;
                    lv[j] = f2bf(x - bf2f(h));
                }
                rhi[kt] = __builtin_bit_cast(bf16x8, hv);
                rlo[kt] = __builtin_bit_cast(bf16x8, lv);
            }
            f32x4 acc;
            #pragma unroll
            for (int r = 0; r < 4; r++)
                acc[r] = rbuf[(mtS * 16 + q4 * 4 + r) * 68 + ptS * 16 + col] * cb;
            acc = __builtin_amdgcn_mfma_f32_16x16x32_bf16(rhi[0], S0, acc, 0, 0, 0);
            acc = __builtin_amdgcn_mfma_f32_16x16x32_bf16(rlo[0], S0, acc, 0, 0, 0);
            acc = __builtin_amdgcn_mfma_f32_16x16x32_bf16(rhi[1], S1, acc, 0, 0, 0);
            acc = __builtin_amdgcn_mfma_f32_16x16x32_bf16(rlo[1], S1, acc, 0, 0, 0);
            #pragma unroll
            for (int r = 0; r < 4; r++)
                Ab[ia_next][(mtS * 16 + q4 * 4 + r) * 68 + ptS * 16 + col] = acc[r];
        }
        __syncthreads();

        if (k == NSTEP - 1 && blk == 0) {
            for (int i = t; i < 2048; i += 512)
                out[i] = (Ab[ia_next][(i >> 6) * 68 + (i & 63)] - state[i]) * INV_DT_SKIP;
        }

        int tmp = ia_prev; ia_prev = ia_cur; ia_cur = ia_next; ia_next = tmp;
    }
}

// ---------------------------------------------------------------------------
extern "C" void kernel_launch(void* const* d_in, const int* in_sizes, int n_in,
                              void* d_out, int out_size, void* d_ws, size_t ws_size,
                              hipStream_t stream) {
    const float* state = (const float*)d_in[0];   // (32, 64)
    const float* Ap    = (const float*)d_in[1];   // (64, 64)
    const float* Wu    = (const float*)d_in[2];   // (32000, 64)
    const float* Wv    = (const float*)d_in[3];   // (32000, 64)
    const float* Pp    = (const float*)d_in[4];   // (64, 16000)
    float* out = (float*)d_out;
    float* ws  = (float*)d_ws;

    float* inv1 = ws;                               // 4096 floats
    float* inv2 = ws + 4096;                        // 4096 floats
    unsigned* flags = (unsigned*)(ws + 8192);       // NBLK u32 (pad to 64)
    unsigned* pbuf  = (unsigned*)(ws + 8192 + 64);  // 2 x 32 x 1024 u32

    hipLaunchKernelGGL(kzero, dim3(1), dim3(64), 0, stream, flags);
    hipLaunchKernelGGL(kinv, dim3(2), dim3(256), 0, stream, Ap, inv1, inv2);
    hipLaunchKernelGGL(kmain, dim3(NBLK), dim3(512), 0, stream,
                       state, Wu, Wv, Pp, inv1, inv2, pbuf, flags, out);
}